// Round 1
// baseline (159.541 us; speedup 1.0000x reference)
//
#include <hip/hip_runtime.h>

#define HH 256
#define WW 128
#define PSZ 16
#define NPH 16
#define NPW 8
#define PP 128
#define DD 256
#define HID 8
#define NBLK 8

__global__ __launch_bounds__(256, 2)
void lca_kernel(const float* __restrict__ x, const float* __restrict__ We,
                const float* __restrict__ be, const float* __restrict__ Wd,
                const float* __restrict__ bd, float* __restrict__ out) {
    const int wg  = blockIdx.x;
    const int ph  = wg >> 8;        // 0..15  (grid = 16 * 256)
    const int nb  = wg & 255;       // 0..255
    const int tid = threadIdx.x;
    const int wave = tid >> 6;
    const int lane = tid & 63;
    const int half = lane >> 5;
    const int l    = lane & 31;     // lane within half-wave (patch group)
    const int pw   = wave * 2 + half;
    const int p    = ph * NPW + pw;

    // ---- preload per-lane weights into registers ----
    // lane owns patch elements d = k*32 + l, k = 0..7
    float we[HID][8];   // we[h][k] = We[p][h][k*32+l]
    float wd[8][HID];   // wd[k][h] = Wd[p][k*32+l][h]
    float bdv[8];
    float bev[HID];
#pragma unroll
    for (int h = 0; h < HID; ++h) {
        const float* wp = We + ((size_t)p * HID + h) * DD + l;
#pragma unroll
        for (int k = 0; k < 8; ++k) we[h][k] = wp[k * 32];
        bev[h] = be[p * HID + h];
    }
#pragma unroll
    for (int k = 0; k < 8; ++k) {
        const float4* wp = (const float4*)(Wd + ((size_t)p * DD + k * 32 + l) * HID);
        float4 a = wp[0], b = wp[1];
        wd[k][0] = a.x; wd[k][1] = a.y; wd[k][2] = a.z; wd[k][3] = a.w;
        wd[k][4] = b.x; wd[k][5] = b.y; wd[k][6] = b.z; wd[k][7] = b.w;
        bdv[k] = bd[p * DD + k * 32 + l];
    }

    // element d = k*32+l -> patch row i = 2k + (l>>4), patch col j = l&15
    const int rbase = ph * PSZ;
    const int colp  = pw * PSZ + (l & 15);
    const int r0    = l >> 4;   // 0 or 1
    // flat offset for k-th element: (rbase + 2k + r0)*WW + colp
    const int off0  = (rbase + r0) * WW + colp;

    for (int nn = 0; nn < NBLK; ++nn) {
        const int n = nb * NBLK + nn;
        const float* xn = x   + (size_t)n * (HH * WW);
        float*       on = out + (size_t)n * (HH * WW);

        // gather this lane's 8 patch elements (per-wave: 2 full 128B lines per k)
        float xv[8];
#pragma unroll
        for (int k = 0; k < 8; ++k)
            xv[k] = xn[off0 + k * 2 * WW];

        // encode: per-lane partial dot products for all 8 hidden units
        float z[HID];
#pragma unroll
        for (int h = 0; h < HID; ++h) {
            float s = 0.f;
#pragma unroll
            for (int k = 0; k < 8; ++k) s = fmaf(we[h][k], xv[k], s);
            z[h] = s;
        }
        // butterfly reduce across the 32-lane half (masks <32 stay in-half)
#pragma unroll
        for (int m = 1; m < 32; m <<= 1) {
#pragma unroll
            for (int h = 0; h < HID; ++h)
                z[h] += __shfl_xor(z[h], m);
        }
#pragma unroll
        for (int h = 0; h < HID; ++h) z[h] += bev[h];

        // decode + bias + sigmoid + store
#pragma unroll
        for (int k = 0; k < 8; ++k) {
            float s = bdv[k];
#pragma unroll
            for (int h = 0; h < HID; ++h) s = fmaf(wd[k][h], z[h], s);
            float o = 1.0f / (1.0f + __expf(-s));
            on[off0 + k * 2 * WW] = o;
        }
    }
}

extern "C" void kernel_launch(void* const* d_in, const int* in_sizes, int n_in,
                              void* d_out, int out_size, void* d_ws, size_t ws_size,
                              hipStream_t stream) {
    const float* x  = (const float*)d_in[0];
    const float* We = (const float*)d_in[1];
    const float* be = (const float*)d_in[2];
    const float* Wd = (const float*)d_in[3];
    const float* bd = (const float*)d_in[4];
    float* out = (float*)d_out;

    const int n_total = in_sizes[0] / (HH * WW);   // 2048
    const int grid = NPH * (n_total / NBLK);       // 16 * 256 = 4096
    lca_kernel<<<dim3(grid), dim3(256), 0, stream>>>(x, We, be, Wd, bd, out);
}

// Round 2
// 148.829 us; speedup vs baseline: 1.0720x; 1.0720x over previous
//
#include <hip/hip_runtime.h>

#define HH 256
#define WW 128
#define DD 256
#define HID 8
#define NBLK 16

typedef float v4f __attribute__((ext_vector_type(4)));

__global__ __launch_bounds__(256, 4)
void lca_kernel(const float* __restrict__ x, const float* __restrict__ We,
                const float* __restrict__ be, const float* __restrict__ Wd,
                const float* __restrict__ bd, float* __restrict__ out) {
    const int bid  = blockIdx.x;
    const int pg   = bid >> 7;        // 0..31 : group of 4 adjacent patches
    const int nb   = bid & 127;       // 0..127 : sample block
    const int tid  = threadIdx.x;
    const int wave = tid >> 6;
    const int lane = tid & 63;
    const int p    = pg * 4 + wave;   // patch 0..127 (one wave per patch)
    const int ph   = p >> 3, pw = p & 7;

    // lane owns d = 4*lane .. 4*lane+3  ->  patch row i = lane>>2, col j = (lane&3)*4
    const int i = lane >> 2, j = (lane & 3) * 4;
    const int off0 = (ph * 16 + i) * WW + pw * 16 + j;

    // ---- weight preload into registers ----
    v4f we4[HID];
#pragma unroll
    for (int h = 0; h < HID; ++h)
        we4[h] = *(const v4f*)(We + ((size_t)(p * HID + h)) * DD + lane * 4);
    float bev[HID];
#pragma unroll
    for (int h = 0; h < HID; ++h) bev[h] = be[p * HID + h];
    v4f wd4[4][2];
#pragma unroll
    for (int c = 0; c < 4; ++c) {
        const v4f* wp = (const v4f*)(Wd + ((size_t)(p * DD + lane * 4 + c)) * HID);
        wd4[c][0] = wp[0];
        wd4[c][1] = wp[1];
    }
    v4f bdv = *(const v4f*)(bd + p * DD + lane * 4);

    const bool hi = lane >= 32;
    const float* xp0 = x   + (size_t)(nb * NBLK) * (HH * WW) + off0;
    float*       op0 = out + (size_t)(nb * NBLK) * (HH * WW) + off0;

    for (int nn = 0; nn < NBLK; ++nn) {
        v4f xv = *(const v4f*)(xp0 + (size_t)nn * (HH * WW));

        // encode partials: z[h] = dot(we4[h], xv)
        float z[HID];
#pragma unroll
        for (int h = 0; h < HID; ++h)
            z[h] = fmaf(we4[h].x, xv.x,
                   fmaf(we4[h].y, xv.y,
                   fmaf(we4[h].z, xv.z, we4[h].w * xv.w)));

        // split butterfly: reduce-scatter at mask 32 (low lanes own h0-3)
        float s4[4];
#pragma unroll
        for (int c = 0; c < 4; ++c) {
            float send = hi ? z[c]     : z[c + 4];
            float keep = hi ? z[c + 4] : z[c];
            s4[c] = keep + __shfl_xor(send, 32);
        }
#pragma unroll
        for (int m = 16; m >= 1; m >>= 1) {
#pragma unroll
            for (int c = 0; c < 4; ++c) s4[c] += __shfl_xor(s4[c], m);
        }
        // allgather at mask 32
        float zf[HID];
#pragma unroll
        for (int c = 0; c < 4; ++c) {
            float v = __shfl_xor(s4[c], 32);
            zf[c]     = (hi ? v : s4[c]) + bev[c];
            zf[c + 4] = (hi ? s4[c] : v) + bev[c + 4];
        }

        // decode + sigmoid
        v4f o;
#pragma unroll
        for (int c = 0; c < 4; ++c) {
            float s = bdv[c];
#pragma unroll
            for (int h = 0; h < 4; ++h) s = fmaf(wd4[c][0][h], zf[h], s);
#pragma unroll
            for (int h = 0; h < 4; ++h) s = fmaf(wd4[c][1][h], zf[h + 4], s);
            o[c] = 1.0f / (1.0f + __expf(-s));
        }
        __builtin_nontemporal_store(o, (v4f*)(op0 + (size_t)nn * (HH * WW)));
    }
}

extern "C" void kernel_launch(void* const* d_in, const int* in_sizes, int n_in,
                              void* d_out, int out_size, void* d_ws, size_t ws_size,
                              hipStream_t stream) {
    const float* x  = (const float*)d_in[0];
    const float* We = (const float*)d_in[1];
    const float* be = (const float*)d_in[2];
    const float* Wd = (const float*)d_in[3];
    const float* bd = (const float*)d_in[4];
    float* out = (float*)d_out;

    const int n_total = in_sizes[0] / (HH * WW);            // 2048
    const int grid    = 32 * (n_total / NBLK);              // 32 * 128 = 4096
    lca_kernel<<<dim3(grid), dim3(256), 0, stream>>>(x, We, be, Wd, bd, out);
}

// Round 3
// 145.215 us; speedup vs baseline: 1.0987x; 1.0249x over previous
//
#include <hip/hip_runtime.h>

#define HH 256
#define WW 128
#define DD 256
#define HID 8
#define NBLK 16
#define UNR 4

typedef float v4f __attribute__((ext_vector_type(4)));

#define KEEP4(v) asm volatile("" : "+v"((v).x), "+v"((v).y), "+v"((v).z), "+v"((v).w))

__global__ __launch_bounds__(256, 4)
void lca_kernel(const float* __restrict__ x, const float* __restrict__ We,
                const float* __restrict__ be, const float* __restrict__ Wd,
                const float* __restrict__ bd, float* __restrict__ out) {
    const int bid  = blockIdx.x;
    const int pg   = bid >> 7;        // 0..31 : group of 4 adjacent patches
    const int nb   = bid & 127;       // 0..127 : sample block
    const int tid  = threadIdx.x;
    const int wave = tid >> 6;
    const int lane = tid & 63;
    const int p    = pg * 4 + wave;   // patch 0..127 (one wave per patch)
    const int ph   = p >> 3, pw = p & 7;

    // lane owns d = 4*lane .. 4*lane+3 -> patch row i = lane>>2, col j = (lane&3)*4
    const int i = lane >> 2, j = (lane & 3) * 4;
    const int off0 = (ph * 16 + i) * WW + pw * 16 + j;

    // ---- weight preload into registers (pinned) ----
    v4f we4[HID];
#pragma unroll
    for (int h = 0; h < HID; ++h)
        we4[h] = *(const v4f*)(We + ((size_t)(p * HID + h)) * DD + lane * 4);
    float bev[HID];
#pragma unroll
    for (int h = 0; h < HID; ++h) bev[h] = be[p * HID + h];
    v4f wd4[4][2];
#pragma unroll
    for (int c = 0; c < 4; ++c) {
        const v4f* wp = (const v4f*)(Wd + ((size_t)(p * DD + lane * 4 + c)) * HID);
        wd4[c][0] = wp[0];
        wd4[c][1] = wp[1];
    }
    v4f bdv = *(const v4f*)(bd + p * DD + lane * 4);

    // keepalive: force all weight loads to complete here and stay in VGPRs
#pragma unroll
    for (int h = 0; h < HID; ++h) KEEP4(we4[h]);
#pragma unroll
    for (int c = 0; c < 4; ++c) { KEEP4(wd4[c][0]); KEEP4(wd4[c][1]); }

    const bool hi = lane >= 32;
    const float* xp0 = x   + (size_t)(nb * NBLK) * (HH * WW) + off0;
    float*       op0 = out + (size_t)(nb * NBLK) * (HH * WW) + off0;

    for (int nn = 0; nn < NBLK; nn += UNR) {
        // load UNR samples' fragments
        v4f xv[UNR];
#pragma unroll
        for (int u = 0; u < UNR; ++u)
            xv[u] = *(const v4f*)(xp0 + (size_t)(nn + u) * (HH * WW));

        // encode partials + reduce-scatter at mask 32 (low lanes own h0-3, high h4-7)
        float s4[UNR][4];
#pragma unroll
        for (int u = 0; u < UNR; ++u) {
            float z[HID];
#pragma unroll
            for (int h = 0; h < HID; ++h)
                z[h] = fmaf(we4[h].x, xv[u].x,
                       fmaf(we4[h].y, xv[u].y,
                       fmaf(we4[h].z, xv[u].z, we4[h].w * xv[u].w)));
#pragma unroll
            for (int c = 0; c < 4; ++c) {
                float send = hi ? z[c]     : z[c + 4];
                float keep = hi ? z[c + 4] : z[c];
                s4[u][c] = keep + __shfl_xor(send, 32);
            }
        }

        // butterfly stages interleaved across the UNR independent samples (ILP)
#pragma unroll
        for (int m = 16; m >= 1; m >>= 1) {
#pragma unroll
            for (int u = 0; u < UNR; ++u)
#pragma unroll
                for (int c = 0; c < 4; ++c)
                    s4[u][c] += __shfl_xor(s4[u][c], m);
        }

        // allgather + decode + sigmoid + store per sample
#pragma unroll
        for (int u = 0; u < UNR; ++u) {
            float zf[HID];
#pragma unroll
            for (int c = 0; c < 4; ++c) {
                float v = __shfl_xor(s4[u][c], 32);
                zf[c]     = (hi ? v : s4[u][c]) + bev[c];
                zf[c + 4] = (hi ? s4[u][c] : v) + bev[c + 4];
            }
            v4f o;
#pragma unroll
            for (int c = 0; c < 4; ++c) {
                float s = bdv[c];
#pragma unroll
                for (int h = 0; h < 4; ++h) s = fmaf(wd4[c][0][h], zf[h], s);
#pragma unroll
                for (int h = 0; h < 4; ++h) s = fmaf(wd4[c][1][h], zf[h + 4], s);
                o[c] = 1.0f / (1.0f + __expf(-s));
            }
            *(v4f*)(op0 + (size_t)(nn + u) * (HH * WW)) = o;
        }
    }
}

extern "C" void kernel_launch(void* const* d_in, const int* in_sizes, int n_in,
                              void* d_out, int out_size, void* d_ws, size_t ws_size,
                              hipStream_t stream) {
    const float* x  = (const float*)d_in[0];
    const float* We = (const float*)d_in[1];
    const float* be = (const float*)d_in[2];
    const float* Wd = (const float*)d_in[3];
    const float* bd = (const float*)d_in[4];
    float* out = (float*)d_out;

    const int n_total = in_sizes[0] / (HH * WW);            // 2048
    const int grid    = 32 * (n_total / NBLK);              // 32 * 128 = 4096
    lca_kernel<<<dim3(grid), dim3(256), 0, stream>>>(x, We, be, Wd, bd, out);
}

// Round 4
// 143.186 us; speedup vs baseline: 1.1142x; 1.0142x over previous
//
#include <hip/hip_runtime.h>

#define HH 256
#define WW 128
#define DD 256
#define HID 8
#define NBLK 32
#define UNR 4

typedef float v4f __attribute__((ext_vector_type(4)));

#define KEEP4(v) asm volatile("" : "+v"((v).x), "+v"((v).y), "+v"((v).z), "+v"((v).w))

__device__ __forceinline__ float rlane(float v, int l) {
    return __int_as_float(__builtin_amdgcn_readlane(__float_as_int(v), l));
}

__global__ __launch_bounds__(256, 4)
void lca_kernel(const float* __restrict__ x, const float* __restrict__ We,
                const float* __restrict__ be, const float* __restrict__ Wd,
                const float* __restrict__ bd, float* __restrict__ out) {
    const int bid  = blockIdx.x;
    const int pg   = bid >> 6;        // 0..31 : group of 4 adjacent patches
    const int nb   = bid & 63;        // 0..63 : sample block
    const int tid  = threadIdx.x;
    const int wave = tid >> 6;
    const int lane = tid & 63;
    const int p    = pg * 4 + wave;   // one wave per patch
    const int ph   = p >> 3, pw = p & 7;

    // lane owns d = 4*lane .. 4*lane+3 -> patch row i = lane>>2, col j = (lane&3)*4
    const int i = lane >> 2, j = (lane & 3) * 4;
    const int off0 = (ph * 16 + i) * WW + pw * 16 + j;

    // ---- weight preload into registers ----
    v4f we4[HID];
#pragma unroll
    for (int h = 0; h < HID; ++h)
        we4[h] = *(const v4f*)(We + ((size_t)(p * HID + h)) * DD + lane * 4);
    float bev[HID];
#pragma unroll
    for (int h = 0; h < HID; ++h) bev[h] = be[p * HID + h];
    v4f wd4[4][2];
#pragma unroll
    for (int c = 0; c < 4; ++c) {
        const v4f* wp = (const v4f*)(Wd + ((size_t)(p * DD + lane * 4 + c)) * HID);
        wd4[c][0] = wp[0];
        wd4[c][1] = wp[1];
    }
    v4f bdv = *(const v4f*)(bd + p * DD + lane * 4);

#pragma unroll
    for (int h = 0; h < HID; ++h) KEEP4(we4[h]);
#pragma unroll
    for (int c = 0; c < 4; ++c) { KEEP4(wd4[c][0]); KEEP4(wd4[c][1]); }

    const bool b5 = (lane & 32) != 0;
    const bool b4 = (lane & 16) != 0;
    const bool b3 = (lane & 8)  != 0;

    const float* xp0 = x   + (size_t)(nb * NBLK) * (HH * WW) + off0;
    float*       op0 = out + (size_t)(nb * NBLK) * (HH * WW) + off0;

    for (int nn = 0; nn < NBLK; nn += UNR) {
        // load UNR samples' fragments (one dwordx4 per lane each)
        v4f xv[UNR];
#pragma unroll
        for (int u = 0; u < UNR; ++u)
            xv[u] = *(const v4f*)(xp0 + (size_t)(nn + u) * (HH * WW));

        // encode partials + reduce-scatter stage mask32 (keep 4 of 8)
        float a[UNR][4];
#pragma unroll
        for (int u = 0; u < UNR; ++u) {
            float z[HID];
#pragma unroll
            for (int h = 0; h < HID; ++h)
                z[h] = fmaf(we4[h].x, xv[u].x,
                       fmaf(we4[h].y, xv[u].y,
                       fmaf(we4[h].z, xv[u].z, we4[h].w * xv[u].w)));
#pragma unroll
            for (int c = 0; c < 4; ++c) {
                float send = b5 ? z[c]     : z[c + 4];
                float keep = b5 ? z[c + 4] : z[c];
                a[u][c] = keep + __shfl_xor(send, 32);
            }
        }

        // stage mask16 (keep 2 of 4)
        float bb[UNR][2];
#pragma unroll
        for (int u = 0; u < UNR; ++u) {
#pragma unroll
            for (int c = 0; c < 2; ++c) {
                float send = b4 ? a[u][c]     : a[u][c + 2];
                float keep = b4 ? a[u][c + 2] : a[u][c];
                bb[u][c] = keep + __shfl_xor(send, 16);
            }
        }

        // stage mask8 (keep 1 of 2); lane now owns h = 4*b5 + 2*b4 + b3
        float s1[UNR];
#pragma unroll
        for (int u = 0; u < UNR; ++u) {
            float send = b3 ? bb[u][0] : bb[u][1];
            float keep = b3 ? bb[u][1] : bb[u][0];
            s1[u] = keep + __shfl_xor(send, 8);
        }

        // finish reduction over lane bits 2:0 (full butterfly, 3 stages)
#pragma unroll
        for (int m = 4; m >= 1; m >>= 1) {
#pragma unroll
            for (int u = 0; u < UNR; ++u)
                s1[u] += __shfl_xor(s1[u], m);
        }

        // broadcast via readlane (h lives at lane h*8) + decode + sigmoid + store
#pragma unroll
        for (int u = 0; u < UNR; ++u) {
            float zf[HID];
#pragma unroll
            for (int h = 0; h < HID; ++h)
                zf[h] = rlane(s1[u], h * 8) + bev[h];

            v4f o;
#pragma unroll
            for (int c = 0; c < 4; ++c) {
                float s = bdv[c];
#pragma unroll
                for (int h = 0; h < 4; ++h) s = fmaf(wd4[c][0][h], zf[h], s);
#pragma unroll
                for (int h = 0; h < 4; ++h) s = fmaf(wd4[c][1][h], zf[h + 4], s);
                o[c] = __builtin_amdgcn_rcpf(1.0f + __expf(-s));
            }
            *(v4f*)(op0 + (size_t)(nn + u) * (HH * WW)) = o;
        }
    }
}

extern "C" void kernel_launch(void* const* d_in, const int* in_sizes, int n_in,
                              void* d_out, int out_size, void* d_ws, size_t ws_size,
                              hipStream_t stream) {
    const float* x  = (const float*)d_in[0];
    const float* We = (const float*)d_in[1];
    const float* be = (const float*)d_in[2];
    const float* Wd = (const float*)d_in[3];
    const float* bd = (const float*)d_in[4];
    float* out = (float*)d_out;

    const int n_total = in_sizes[0] / (HH * WW);            // 2048
    const int grid    = 32 * (n_total / NBLK);              // 32 * 64 = 2048
    lca_kernel<<<dim3(grid), dim3(256), 0, stream>>>(x, We, be, Wd, bd, out);
}